// Round 1
// 434.048 us; speedup vs baseline: 1.1550x; 1.1550x over previous
//
#include <hip/hip_runtime.h>

#define Bsz  2048
#define Tlen 512
#define Din  32
#define Hd   64
#define BT   16            // real batches per block (N=16 MFMA tile, no ghost rows)
#define HS   72            // h-tile row stride in f16 elems (144B, 16B-aligned reads)
#define BUFE 2048          // f16 elems per h buffer (4096 B)
#define CHUNK 16           // x timesteps per staged chunk
#define NCHUNK (Tlen / CHUNK)
#define XSTRH 1040         // f16 x-chunk bytes per batch (16 steps*64B + 16 pad)
#define XBUFB (BT * XSTRH) // bytes per x chunk buffer (16640)

typedef _Float16 half8 __attribute__((ext_vector_type(8)));
typedef _Float16 half4 __attribute__((ext_vector_type(4)));
typedef float    f32x4 __attribute__((ext_vector_type(4)));

// TRANSPOSED formulation: D = A*B with A = W fragment (rows = gate cols),
// B = h/x fragment (cols = batches). A/B frag layouts are symmetric, so the
// W registers and all LDS read addresses are identical to the untransposed
// version -- only the C/D interpretation changes: lane (quad,m) now holds
// batch m, gate cols gc+{0..3} CONTIGUOUS -> h write is ONE ds_write_b64
// (conflict-free) instead of 4 scattered b16 writes (~4-way conflicted).
#define MFMA(a, b, c) __builtin_amdgcn_mfma_f32_16x16x32_f16((a), (b), (c), 0, 0, 0)

__device__ __forceinline__ half8 load8s(const float* p, float s) {
    half8 r;
#pragma unroll
    for (int j = 0; j < 8; ++j) r[j] = (_Float16)(p[j] * s);
    return r;
}
__device__ __forceinline__ half8 cvt8(float4 a, float4 b) {
    half8 r;
    r[0] = (_Float16)a.x; r[1] = (_Float16)a.y; r[2] = (_Float16)a.z; r[3] = (_Float16)a.w;
    r[4] = (_Float16)b.x; r[5] = (_Float16)b.y; r[6] = (_Float16)b.z; r[7] = (_Float16)b.w;
    return r;
}

// weights pre-scaled by -log2(e) (r,z) and -2*log2(e) (n). With E = 2^(scaled):
//   sigma(raw) = 1/(1+E),  tanh(raw_n) = (1-E_n)/(1+E_n)
// GRU update folds to ONE rcp:  h' = [E_z(1-E_n) + h(1+E_n)] / [(1+E_z)(1+E_n)]
__device__ __forceinline__ void gate_update(const f32x4& gr, const f32x4& gz,
                                            const f32x4& anx, const f32x4& anh,
                                            float hst[4], _Float16* dst, bool wr) {
    half4 pk;
#pragma unroll
    for (int r = 0; r < 4; ++r) {
        float Er = __builtin_amdgcn_exp2f(gr[r]);
        float rr = __builtin_amdgcn_rcpf(1.0f + Er);
        float yy = anx[r] + rr * anh[r];
        float En = __builtin_amdgcn_exp2f(yy);
        float Ez = __builtin_amdgcn_exp2f(gz[r]);
        float num = Ez * (1.0f - En) + hst[r] * (1.0f + En);
        float den = (1.0f + Ez) * (1.0f + En);
        hst[r] = num * __builtin_amdgcn_rcpf(den);
        pk[r] = (_Float16)hst[r];
    }
    if (wr) *(half4*)dst = pk;   // one b64 store, 4 contiguous h cols of batch m
}

__global__ __launch_bounds__(512, 2)
void gru_fused(const float* __restrict__ x,
               const float* __restrict__ Wih0, const float* __restrict__ Whh0,
               const float* __restrict__ bih0, const float* __restrict__ bhh0,
               const float* __restrict__ Wih1, const float* __restrict__ Whh1,
               const float* __restrict__ bih1, const float* __restrict__ bhh1,
               const float* __restrict__ fcw,  const float* __restrict__ fcb,
               float* __restrict__ out)
{
    // arena: h1 buffers at [0],[BUFE]; h2 buffers at [2*BUFE],[3*BUFE]
    __shared__ _Float16 arena[4 * BUFE];
    __shared__ __attribute__((aligned(16))) char xstage[2 * XBUFB];  // f16 x chunks
    __shared__ float hfin[BT][Hd];

    const int tid  = threadIdx.x;
    const int lane = tid & 63;
    const int wave = tid >> 6;
    const int grp  = wave >> 2;            // 0 = layer1 waves, 1 = layer2 waves
    const int wg   = wave & 3;             // which 16 gate-cols this wave owns
    const int m    = lane & 15;            // A row (W row) AND B col (batch)
    const int quad = lane >> 4;            // k-chunk (A/B), row-group (C/D)
    const int col  = (wg << 4) + m;        // W row this lane loads (A-frag)
    const int gc   = (wg << 4) + (quad << 2); // C-frag: gate/h col base this lane owns
    const int b0   = blockIdx.x << 4;      // 16 batches per block

    for (int idx = tid; idx < 4 * BUFE; idx += 512) arena[idx] = (_Float16)0.f;

    // ---- x staging: f32 global -> regs -> f16 LDS; 2 batches per wave ----
    const int sb    = (wave << 1) + (lane >> 5);   // batch this lane stages
    const int st    = (lane & 31) >> 1;            // step-in-chunk
    const int sdh   = lane & 1;                    // din half (0..15 / 16..31)
    const float* xgp = x + (size_t)(b0 + sb) * (Tlen * Din) + st * Din + sdh * 16;
    const int swoff = sb * XSTRH + st * 64 + sdh * 32;

    float4 xh0, xh1, xh2, xh3;
    {   // chunk 0 -> slot 0
        const float* p = xgp;
        xh0 = *(const float4*)p;       xh1 = *(const float4*)(p + 4);
        xh2 = *(const float4*)(p + 8); xh3 = *(const float4*)(p + 12);
        char* wp = xstage + swoff;
        *(half8*)wp        = cvt8(xh0, xh1);
        *(half8*)(wp + 16) = cvt8(xh2, xh3);
    }
    {   // chunk 1 -> slot 1
        const float* p = xgp + CHUNK * Din;
        xh0 = *(const float4*)p;       xh1 = *(const float4*)(p + 4);
        xh2 = *(const float4*)(p + 8); xh3 = *(const float4*)(p + 12);
        char* wp = xstage + XBUFB + swoff;
        *(half8*)wp        = cvt8(xh0, xh1);
        *(half8*)(wp + 16) = cvt8(xh2, xh3);
    }
    {   // chunk 2 -> regs, held until boundary k=1 (hides HBM latency behind a step)
        const float* p = xgp + 2 * CHUNK * Din;
        xh0 = *(const float4*)p;       xh1 = *(const float4*)(p + 4);
        xh2 = *(const float4*)(p + 8); xh3 = *(const float4*)(p + 12);
    }

    const float sRZ = -1.44269504f;        // -log2(e)
    const float sN  = -2.88539008f;        // -2*log2(e)

    // ---- persistent pre-scaled weight A-fragments (A[row=gatecol][k]) ----
    half8 wx[2][3], wh[2][3];
    f32x4 brz0v, brz1v, binv, bhnv;        // per-lane biases, now per gate-col (vec4)

    if (grp == 0) {
        wx[0][0] = load8s(Wih0 + (      col) * Din + quad * 8, sRZ);
        wx[0][1] = load8s(Wih0 + ( 64 + col) * Din + quad * 8, sRZ);
        wx[0][2] = load8s(Wih0 + (128 + col) * Din + quad * 8, sN);
#pragma unroll
        for (int kb = 0; kb < 2; ++kb) {
            wh[kb][0] = load8s(Whh0 + (      col) * Hd + kb * 32 + quad * 8, sRZ);
            wh[kb][1] = load8s(Whh0 + ( 64 + col) * Hd + kb * 32 + quad * 8, sRZ);
            wh[kb][2] = load8s(Whh0 + (128 + col) * Hd + kb * 32 + quad * 8, sN);
        }
#pragma unroll
        for (int r = 0; r < 4; ++r) {
            brz0v[r] = sRZ * (bih0[gc + r] + bhh0[gc + r]);
            brz1v[r] = sRZ * (bih0[64 + gc + r] + bhh0[64 + gc + r]);
            binv[r]  = sN * bih0[128 + gc + r];
            bhnv[r]  = sN * bhh0[128 + gc + r];
        }
    } else {
#pragma unroll
        for (int kb = 0; kb < 2; ++kb) {
            wx[kb][0] = load8s(Wih1 + (      col) * Hd + kb * 32 + quad * 8, sRZ);
            wx[kb][1] = load8s(Wih1 + ( 64 + col) * Hd + kb * 32 + quad * 8, sRZ);
            wx[kb][2] = load8s(Wih1 + (128 + col) * Hd + kb * 32 + quad * 8, sN);
            wh[kb][0] = load8s(Whh1 + (      col) * Hd + kb * 32 + quad * 8, sRZ);
            wh[kb][1] = load8s(Whh1 + ( 64 + col) * Hd + kb * 32 + quad * 8, sRZ);
            wh[kb][2] = load8s(Whh1 + (128 + col) * Hd + kb * 32 + quad * 8, sN);
        }
#pragma unroll
        for (int r = 0; r < 4; ++r) {
            brz0v[r] = sRZ * (bih1[gc + r] + bhh1[gc + r]);
            brz1v[r] = sRZ * (bih1[64 + gc + r] + bhh1[64 + gc + r]);
            binv[r]  = sN * bih1[128 + gc + r];
            bhnv[r]  = sN * bhh1[128 + gc + r];
        }
    }

    const int rdoff  = m * HS + quad * 8;       // B-frag read: batch m, k = quad*8..
    const int xroffH = m * XSTRH + quad * 16;   // x B-frag read (bytes)
    const int wroff  = m * HS + gc;             // C write: row = batch m, cols gc..gc+3
    float hst[4] = {0.f, 0.f, 0.f, 0.f};
    half8 ax;
    __syncthreads();

    // invariant: entering step body for step j, ax holds f16 x[j] frag (grp0 only)
    if (grp == 0) ax = *(const half8*)(xstage + xroffH);   // x[0]

// one recurrence step; RO/WO are compile-time buffer offsets. Ends pre-barrier
// with the x preload for step I+1 (x chunk buffers are stable across barriers).
#define STEP(I, RO, WO)                                                          \
  do {                                                                           \
    if (grp == 0) {                                                              \
      const _Float16* s1 = arena + (RO) + rdoff;                                 \
      half8 bh0 = *(const half8*)s1;                                             \
      half8 bh1 = *(const half8*)(s1 + 32);                                      \
      f32x4 arx = brz0v, azx = brz1v, anx = binv;                                \
      f32x4 arh = {0.f,0.f,0.f,0.f}, azh = {0.f,0.f,0.f,0.f};                    \
      f32x4 anh = bhnv;                                                          \
      arh = MFMA(wh[0][0], bh0, arh); arh = MFMA(wh[1][0], bh1, arh);            \
      azh = MFMA(wh[0][1], bh0, azh); azh = MFMA(wh[1][1], bh1, azh);            \
      anh = MFMA(wh[0][2], bh0, anh); anh = MFMA(wh[1][2], bh1, anh);            \
      arx = MFMA(wx[0][0], ax, arx);                                             \
      azx = MFMA(wx[0][1], ax, azx);                                             \
      anx = MFMA(wx[0][2], ax, anx);                                             \
      f32x4 gr = arx + arh, gz = azx + azh;                                      \
      gate_update(gr, gz, anx, anh, hst, arena + (WO) + wroff, true);            \
      { const int nx = ((I) + 1 < Tlen) ? (I) + 1 : (I);                         \
        ax = *(const half8*)(xstage + ((nx >> 4) & 1) * XBUFB                    \
                             + (nx & 15) * 64 + xroffH); }                       \
    } else {                                                                     \
      const _Float16* s1 = arena + (RO) + rdoff;              /* h1[I-1] */      \
      const _Float16* s2 = s1 + 2 * BUFE;                     /* h2[I-2] */      \
      half8 bx0 = *(const half8*)s1;                                             \
      half8 bx1 = *(const half8*)(s1 + 32);                                      \
      half8 bh0 = *(const half8*)s2;                                             \
      half8 bh1 = *(const half8*)(s2 + 32);                                      \
      f32x4 arx = brz0v, azx = brz1v, anx = binv;                                \
      f32x4 arh = {0.f,0.f,0.f,0.f}, azh = {0.f,0.f,0.f,0.f};                    \
      f32x4 anh = bhnv;                                                          \
      arx = MFMA(wx[0][0], bx0, arx); arx = MFMA(wx[1][0], bx1, arx);            \
      azx = MFMA(wx[0][1], bx0, azx); azx = MFMA(wx[1][1], bx1, azx);            \
      anx = MFMA(wx[0][2], bx0, anx); anx = MFMA(wx[1][2], bx1, anx);            \
      arh = MFMA(wh[0][0], bh0, arh); arh = MFMA(wh[1][0], bh1, arh);            \
      azh = MFMA(wh[0][1], bh0, azh); azh = MFMA(wh[1][1], bh1, azh);            \
      anh = MFMA(wh[0][2], bh0, anh); anh = MFMA(wh[1][2], bh1, anh);            \
      f32x4 gr = arx + arh, gz = azx + azh;                                      \
      gate_update(gr, gz, anx, anh, hst, arena + 2 * BUFE + (WO) + wroff,        \
                  true);                                                         \
    }                                                                            \
    __syncthreads();                                                             \
  } while (0)

    // ---------- peel i = 0 : L1 only; h1[-1]=0 so h-side MFMAs are skipped ----------
    if (grp == 0) {
        f32x4 gr = brz0v, gz = brz1v, anx = binv, anh = bhnv;
        gr  = MFMA(wx[0][0], ax, gr);
        gz  = MFMA(wx[0][1], ax, gz);
        anx = MFMA(wx[0][2], ax, anx);
        gate_update(gr, gz, anx, anh, hst, arena + 0 + wroff, true);
        ax = *(const half8*)(xstage + 1 * 64 + xroffH);    // x[1] (chunk 0, slot 1)
    }
    __syncthreads();

    // ---------- main: steps 1..511; odd steps read buf0/write buf1, even reverse ----
    for (int i = 1; i + 1 < Tlen; i += 2) {
        STEP(i, 0, BUFE);                          // odd step
        if (((i + 1) & (CHUNK - 1)) == 0) {
            const int k = (i + 1) >> 4;            // chunk boundary k (1..31)
            if (k + 1 < NCHUNK) {                  // write chunk k+1 (regs -> f16 LDS)
                char* wp = xstage + ((k + 1) & 1) * XBUFB + swoff;
                *(half8*)wp        = cvt8(xh0, xh1);
                *(half8*)(wp + 16) = cvt8(xh2, xh3);
            }
            if (k + 2 < NCHUNK) {                  // issue loads for chunk k+2
                const float* p = xgp + (size_t)(k + 2) * (CHUNK * Din);
                xh0 = *(const float4*)p;       xh1 = *(const float4*)(p + 4);
                xh2 = *(const float4*)(p + 8); xh3 = *(const float4*)(p + 12);
            }
        }
        STEP(i + 1, BUFE, 0);                      // even step
    }
    STEP(Tlen - 1, 0, BUFE);                       // step 511

    // ---------- peel i = T : L2 only, computes h2[T-1], no LDS writeback ----------
    if (grp == 1) {
        const _Float16* s1 = arena + BUFE + rdoff;            // h1[511]
        const _Float16* s2 = s1 + 2 * BUFE;                   // h2[510]
        half8 bx0 = *(const half8*)s1;
        half8 bx1 = *(const half8*)(s1 + 32);
        half8 bh0 = *(const half8*)s2;
        half8 bh1 = *(const half8*)(s2 + 32);
        f32x4 arx = brz0v, azx = brz1v, anx = binv;
        f32x4 arh = {0.f,0.f,0.f,0.f}, azh = {0.f,0.f,0.f,0.f};
        f32x4 anh = bhnv;
        arx = MFMA(wx[0][0], bx0, arx); arx = MFMA(wx[1][0], bx1, arx);
        azx = MFMA(wx[0][1], bx0, azx); azx = MFMA(wx[1][1], bx1, azx);
        anx = MFMA(wx[0][2], bx0, anx); anx = MFMA(wx[1][2], bx1, anx);
        arh = MFMA(wh[0][0], bh0, arh); arh = MFMA(wh[1][0], bh1, arh);
        azh = MFMA(wh[0][1], bh0, azh); azh = MFMA(wh[1][1], bh1, azh);
        anh = MFMA(wh[0][2], bh0, anh); anh = MFMA(wh[1][2], bh1, anh);
        f32x4 gr = arx + arh, gz = azx + azh;
        gate_update(gr, gz, anx, anh, hst, nullptr, false);
        f32x4 fv;
#pragma unroll
        for (int r = 0; r < 4; ++r) fv[r] = hst[r];
        *(f32x4*)(&hfin[m][gc]) = fv;              // batch m, cols gc..gc+3 (float4)
    }
    __syncthreads();
    if (tid < BT) {                                // FC head
        float acc = fcb[0];
        for (int c = 0; c < Hd; ++c) acc += hfin[tid][c] * fcw[c];
        out[b0 + tid] = acc;
    }
#undef STEP
}

extern "C" void kernel_launch(void* const* d_in, const int* in_sizes, int n_in,
                              void* d_out, int out_size, void* d_ws, size_t ws_size,
                              hipStream_t stream) {
    gru_fused<<<dim3(Bsz / BT), dim3(512), 0, stream>>>(
        (const float*)d_in[0],
        (const float*)d_in[1], (const float*)d_in[2],
        (const float*)d_in[3], (const float*)d_in[4],
        (const float*)d_in[5], (const float*)d_in[6],
        (const float*)d_in[7], (const float*)d_in[8],
        (const float*)d_in[9], (const float*)d_in[10],
        (float*)d_out);
}